// Round 2
// baseline (506.311 us; speedup 1.0000x reference)
//
#include <hip/hip_runtime.h>

typedef __bf16 bf16x8 __attribute__((ext_vector_type(8)));
typedef float  f32x4  __attribute__((ext_vector_type(4)));
typedef unsigned short u16;
typedef unsigned int   u32;
typedef long long      i64;

__device__ __forceinline__ float b2f(u16 x){ return __uint_as_float(((u32)x) << 16); }
__device__ __forceinline__ u16 f2b(float x){
  u32 u = __float_as_uint(x);
  return (u16)((u + 0x7FFFu + ((u >> 16) & 1u)) >> 16);
}

// flags[0] = 1 if float tensors are f32 on device (else bf16)
// flags[1] = 1 if edge_index is int64 on device (else int32)
__global__ __launch_bounds__(256) void k_detect(const u16* __restrict__ x,
                                                const u32* __restrict__ ei,
                                                int* __restrict__ flags){
  __shared__ int sh[2];
  int t = threadIdx.x;
  if (t < 2) sh[t] = 0;
  __syncthreads();
  int sane = 0;
  for (int i = t; i < 4096; i += 256){
    u16 u = x[i]; u32 e = (u >> 7) & 0xFFu;
    if (u == 0 || (e >= 0x70u && e <= 0x8Fu)) sane++;
  }
  int nz = 0;
  for (int i = t; i < 1024; i += 256)
    if (ei[2*i + 1] != 0u) nz++;
  atomicAdd(&sh[0], sane);
  atomicAdd(&sh[1], nz);
  __syncthreads();
  if (t == 0){
    flags[0] = (sh[0] < 3500) ? 1 : 0;  // many insane bf16 patterns -> actually f32
    flags[1] = (sh[1] == 0) ? 1 : 0;    // all high halves zero -> int64
  }
}

__device__ __forceinline__ int ld_idx(const void* ei, long long j, int is64){
  return is64 ? (int)((const i64*)ei)[j] : ((const int*)ei)[j];
}
__device__ __forceinline__ float ld_f(const void* p, int j, int isf32){
  return isf32 ? ((const float*)p)[j] : b2f(((const u16*)p)[j]);
}

__global__ void k_zero(int* __restrict__ a, int* __restrict__ b, int n){
  int i = blockIdx.x*blockDim.x + threadIdx.x;
  if (i < n){ a[i] = 0; b[i] = 0; }
}

__global__ void k_deg(const void* __restrict__ ei, int E, int n,
                      int* __restrict__ deg, const int* __restrict__ flags){
  int e = blockIdx.x*blockDim.x + threadIdx.x;
  if (e >= E) return;
  int is64 = flags[1];
  int d = ld_idx(ei, (long long)E + e, is64);
  if ((unsigned)d < (unsigned)n) atomicAdd(&deg[d], 1);
}

// exclusive scan of deg -> rowptr (single block, 1024 threads)
__global__ void k_scan(const int* __restrict__ deg, int* __restrict__ rowptr, int n){
  __shared__ int part[1024];
  int tid = threadIdx.x;
  int chunk = (n + 1023) >> 10;
  int base = tid * chunk;
  int s = 0;
  for (int i = 0; i < chunk; ++i){ int idx = base + i; if (idx < n) s += deg[idx]; }
  part[tid] = s; __syncthreads();
  for (int off = 1; off < 1024; off <<= 1){
    int v = 0; if (tid >= off) v = part[tid - off];
    __syncthreads(); part[tid] += v; __syncthreads();
  }
  int run = part[tid] - s;
  for (int i = 0; i < chunk; ++i){ int idx = base + i; if (idx < n){ rowptr[idx] = run; run += deg[idx]; } }
  if (tid == 1023) rowptr[n] = part[1023];
}

__global__ void k_dis(const int* __restrict__ deg, float* __restrict__ dis, int n){
  int v = blockIdx.x*blockDim.x + threadIdx.x;
  if (v < n) dis[v] = rsqrtf((float)(deg[v] + 1));
}

__global__ void k_fill(const void* __restrict__ ei, int E, int n,
                       const int* __restrict__ rowptr, int* __restrict__ cursor,
                       int* __restrict__ colx, const int* __restrict__ flags){
  int e = blockIdx.x*blockDim.x + threadIdx.x;
  if (e >= E) return;
  int is64 = flags[1];
  int d = ld_idx(ei, (long long)E + e, is64);
  int s = ld_idx(ei, e, is64);
  if ((unsigned)d < (unsigned)n && (unsigned)s < (unsigned)n){
    int p = atomicAdd(&cursor[d], 1);
    colx[rowptr[d] + p] = s;
  }
}

// pre-shuffle W (128x128) into MFMA B-fragment order (bf16 out)
// frag id = nt*4+kk; lane l holds B[k][n], n = nt*16+(l&15),
// elem i -> k = kk*32 + (l>>4)*4 + (i&3) + (i>>2)*16
__global__ __launch_bounds__(64) void k_shufW(const void* __restrict__ W, u16* __restrict__ Ws,
                                              const int* __restrict__ flags){
  int f = flags[0];
  int bid = blockIdx.x;          // 0..31
  int nt = bid >> 2, kk = bid & 3;
  int l = threadIdx.x;
  int g = l >> 4, mr = l & 15;
  int nn = nt*16 + mr;
  #pragma unroll
  for (int i = 0; i < 8; ++i){
    int k = kk*32 + g*4 + (i & 3) + ((i >> 2) << 4);
    u16 w = f ? f2b(((const float*)W)[k*128 + nn]) : ((const u16*)W)[k*128 + nn];
    Ws[(size_t)(bid*64 + l)*8 + i] = w;
  }
}

// T = (A @ W) * dis[row], bf16 out. One wave per 16-row tile.
__global__ __launch_bounds__(256) void k_gemm(const void* __restrict__ A, int aExt,
    const u16* __restrict__ Ws, const float* __restrict__ dis,
    u16* __restrict__ T, int nTiles, const int* __restrict__ flags)
{
  int wave = threadIdx.x >> 6, lane = threadIdx.x & 63;
  int tile = blockIdx.x*4 + wave;
  if (tile >= nTiles) return;
  int g = lane >> 4, mr = lane & 15;
  int f = aExt ? flags[0] : 0;
  union U8 { ushort4 q[2]; u16 s[8]; bf16x8 b; };
  bf16x8 a[4];
  if (f){
    const float* ap = (const float*)A + (size_t)(tile*16 + mr)*128;
    #pragma unroll
    for (int kk = 0; kk < 4; ++kk){
      float4 p = *(const float4*)(ap + kk*32 + g*4);
      float4 q = *(const float4*)(ap + kk*32 + g*4 + 16);
      U8 u;
      u.s[0]=f2b(p.x); u.s[1]=f2b(p.y); u.s[2]=f2b(p.z); u.s[3]=f2b(p.w);
      u.s[4]=f2b(q.x); u.s[5]=f2b(q.y); u.s[6]=f2b(q.z); u.s[7]=f2b(q.w);
      a[kk] = u.b;
    }
  } else {
    const u16* ap = (const u16*)A + (size_t)(tile*16 + mr)*128;
    #pragma unroll
    for (int kk = 0; kk < 4; ++kk){
      U8 u;
      u.q[0] = *(const ushort4*)(ap + kk*32 + g*4);
      u.q[1] = *(const ushort4*)(ap + kk*32 + g*4 + 16);
      a[kk] = u.b;
    }
  }
  float dj[4];
  #pragma unroll
  for (int j = 0; j < 4; ++j) dj[j] = dis[tile*16 + g*4 + j];
  #pragma unroll
  for (int nt = 0; nt < 8; ++nt){
    f32x4 acc = {0.f,0.f,0.f,0.f};
    #pragma unroll
    for (int kk = 0; kk < 4; ++kk){
      bf16x8 b = *(const bf16x8*)(Ws + (size_t)((nt*4 + kk)*64 + lane)*8);
      acc = __builtin_amdgcn_mfma_f32_16x16x32_bf16(a[kk], b, acc, 0, 0, 0);
    }
    int nn = nt*16 + mr;
    #pragma unroll
    for (int j = 0; j < 4; ++j){
      int row = tile*16 + g*4 + j;
      T[(size_t)row*128 + nn] = f2b(acc[j] * dj[j]);
    }
  }
}

// aggregation + bias + epilogue. One wave per node.
// MODE 0: outA (bf16, internal) = LN(relu(agg))
// MODE 1: outA (out dtype per flag) = emb (pre-relu)
template<int MODE>
__global__ __launch_bounds__(64) void k_agg(const u16* __restrict__ T,
    const int* __restrict__ rowptr, const int* __restrict__ colx,
    const float* __restrict__ dis, const void* __restrict__ bias,
    const void* __restrict__ lg, const void* __restrict__ lb,
    void* __restrict__ outA, int n, const int* __restrict__ flags)
{
  int v = blockIdx.x; if (v >= n) return;
  int f = flags[0];
  int l = threadIdx.x, d0 = l*2;
  u32 self = *(const u32*)(T + (size_t)v*128 + d0);
  float a0 = b2f((u16)(self & 0xffff)), a1 = b2f((u16)(self >> 16));
  int s = rowptr[v], e = rowptr[v+1];
  for (int i = s; i < e; ++i){
    int nb = colx[i];
    if ((unsigned)nb >= (unsigned)n) continue;
    u32 u = *(const u32*)(T + (size_t)nb*128 + d0);
    a0 += b2f((u16)(u & 0xffff));
    a1 += b2f((u16)(u >> 16));
  }
  float sc = dis[v];
  float x0 = fmaf(a0, sc, ld_f(bias, d0,   f));
  float x1 = fmaf(a1, sc, ld_f(bias, d0+1, f));
  if (MODE == 0){
    x0 = fmaxf(x0, 0.f); x1 = fmaxf(x1, 0.f);
    float sum = x0 + x1;
    #pragma unroll
    for (int off = 32; off; off >>= 1) sum += __shfl_xor(sum, off);
    float mu = sum * (1.f/128.f);
    float e0 = x0 - mu, e1 = x1 - mu;
    float vs = e0*e0 + e1*e1;
    #pragma unroll
    for (int off = 32; off; off >>= 1) vs += __shfl_xor(vs, off);
    float inv = rsqrtf(vs*(1.f/128.f) + 1e-5f);
    u16* oa = (u16*)outA;
    oa[(size_t)v*128 + d0]   = f2b(e0*inv*ld_f(lg, d0,   f) + ld_f(lb, d0,   f));
    oa[(size_t)v*128 + d0+1] = f2b(e1*inv*ld_f(lg, d0+1, f) + ld_f(lb, d0+1, f));
  } else {
    if (f){
      float* oa = (float*)outA;
      oa[(size_t)v*128 + d0]   = x0;
      oa[(size_t)v*128 + d0+1] = x1;
    } else {
      u16* oa = (u16*)outA;
      oa[(size_t)v*128 + d0]   = f2b(x0);
      oa[(size_t)v*128 + d0+1] = f2b(x1);
    }
  }
}

// collapse post_mp: Wc = mpW1 @ mpW2 (128x40), bc = mpb1 @ mpW2 + mpb2
__global__ __launch_bounds__(128) void k_wc(const void* __restrict__ mpW1, const void* __restrict__ mpb1,
    const void* __restrict__ mpW2, const void* __restrict__ mpb2,
    float* __restrict__ Wc, float* __restrict__ bc, const int* __restrict__ flags)
{
  int f = flags[0];
  int c = blockIdx.x;   // 0..39
  int k = threadIdx.x;  // 0..127
  float acc = 0.f;
  for (int j = 0; j < 128; ++j)
    acc += ld_f(mpW1, k*128 + j, f) * ld_f(mpW2, j*40 + c, f);
  Wc[k*40 + c] = acc;
  if (k == 0){
    float b = ld_f(mpb2, c, f);
    for (int j = 0; j < 128; ++j) b += ld_f(mpb1, j, f) * ld_f(mpW2, j*40 + c, f);
    bc[c] = b;
  }
}

// logits + log_softmax from emb (applies relu on the fly). One wave per node.
__global__ __launch_bounds__(64) void k_logits(const float* __restrict__ Wc,
    const float* __restrict__ bc, void* __restrict__ dout, int n,
    const int* __restrict__ flags)
{
  int v = blockIdx.x; if (v >= n) return;
  int f = flags[0];
  int c = threadIdx.x;
  float acc = -3.0e38f;
  if (c < 40){
    acc = bc[c];
    if (f){
      const float* h = (const float*)dout + (size_t)v*128;
      for (int k = 0; k < 128; ++k) acc = fmaf(fmaxf(h[k], 0.f), Wc[k*40 + c], acc);
    } else {
      const u16* h = (const u16*)dout + (size_t)v*128;
      for (int k = 0; k < 128; ++k) acc = fmaf(fmaxf(b2f(h[k]), 0.f), Wc[k*40 + c], acc);
    }
  }
  float m = acc;
  #pragma unroll
  for (int off = 32; off; off >>= 1) m = fmaxf(m, __shfl_xor(m, off));
  float ex = (c < 40) ? expf(acc - m) : 0.f;
  float ssum = ex;
  #pragma unroll
  for (int off = 32; off; off >>= 1) ssum += __shfl_xor(ssum, off);
  if (c < 40){
    float r = acc - m - logf(ssum);
    if (f) ((float*)dout + (size_t)n*128)[(size_t)v*40 + c] = r;
    else   ((u16*) dout + (size_t)n*128)[(size_t)v*40 + c] = f2b(r);
  }
}

extern "C" void kernel_launch(void* const* d_in, const int* in_sizes, int n_in,
                              void* d_out, int out_size, void* d_ws, size_t ws_size,
                              hipStream_t stream)
{
  const int n = in_sizes[0] / 128;
  const int E = in_sizes[1] / 2;

  const void* x    = d_in[0];
  const void* ei   = d_in[1];
  const void* W1   = d_in[2];
  const void* b1   = d_in[3];
  const void* W2   = d_in[4];
  const void* b2   = d_in[5];
  const void* W3   = d_in[6];
  const void* b3   = d_in[7];
  const void* ln1g = d_in[8];
  const void* ln1b = d_in[9];
  const void* ln2g = d_in[10];
  const void* ln2b = d_in[11];
  const void* mpW1 = d_in[12];
  const void* mpb1 = d_in[13];
  const void* mpW2 = d_in[14];
  const void* mpb2 = d_in[15];

  // Hbuf lives in d_out's emb region (dead until layer-3 epilogue overwrites it)
  u16* Hbuf = (u16*)d_out;

  char* w = (char*)d_ws;
  size_t off = 0;
  auto alloc = [&](size_t bytes)->char*{
    char* p = w + off; off = (off + bytes + 255) & ~(size_t)255; return p;
  };
  int*   flags = (int*)  alloc(256);
  float* dis   = (float*)alloc((size_t)n*4);
  int*   deg   = (int*)  alloc((size_t)n*4);
  int*   rowp  = (int*)  alloc((size_t)(n+1)*4);
  int*   curs  = (int*)  alloc((size_t)n*4);
  int*   colx  = (int*)  alloc((size_t)E*4);
  u16*   T     = (u16*)  alloc((size_t)n*128*2);
  u16*   Ws    = (u16*)  alloc((size_t)128*128*2);
  float* Wc    = (float*)alloc((size_t)128*40*4);
  float* bc    = (float*)alloc((size_t)64*4);

  int gE = (E + 255) / 256;
  int gN = (n + 255) / 256;

  k_detect<<<1, 256, 0, stream>>>((const u16*)x, (const u32*)ei, flags);
  k_zero  <<<gN, 256, 0, stream>>>(deg, curs, n);
  k_deg   <<<gE, 256, 0, stream>>>(ei, E, n, deg, flags);
  k_scan  <<<1, 1024, 0, stream>>>(deg, rowp, n);
  k_dis   <<<gN, 256, 0, stream>>>(deg, dis, n);
  k_fill  <<<gE, 256, 0, stream>>>(ei, E, n, rowp, curs, colx, flags);
  k_wc    <<<40, 128, 0, stream>>>(mpW1, mpb1, mpW2, mpb2, Wc, bc, flags);

  int nTiles = (n + 15) / 16;
  int gG = (nTiles + 3) / 4;

  // layer 0
  k_shufW<<<32, 64, 0, stream>>>(W1, Ws, flags);
  k_gemm <<<gG, 256, 0, stream>>>(x, 1, Ws, dis, T, nTiles, flags);
  k_agg<0><<<n, 64, 0, stream>>>(T, rowp, colx, dis, b1, ln1g, ln1b, Hbuf, n, flags);
  // layer 1
  k_shufW<<<32, 64, 0, stream>>>(W2, Ws, flags);
  k_gemm <<<gG, 256, 0, stream>>>(Hbuf, 0, Ws, dis, T, nTiles, flags);
  k_agg<0><<<n, 64, 0, stream>>>(T, rowp, colx, dis, b2, ln2g, ln2b, Hbuf, n, flags);
  // layer 2: emb = pre-relu conv out -> d_out (overwrites Hbuf region, which is dead now)
  k_shufW<<<32, 64, 0, stream>>>(W3, Ws, flags);
  k_gemm <<<gG, 256, 0, stream>>>(Hbuf, 0, Ws, dis, T, nTiles, flags);
  k_agg<1><<<n, 64, 0, stream>>>(T, rowp, colx, dis, b3, nullptr, nullptr, d_out, n, flags);
  // post_mp collapsed + log_softmax (reads emb with relu on the fly)
  k_logits<<<n, 64, 0, stream>>>(Wc, bc, d_out, n, flags);
}

// Round 3
// 433.064 us; speedup vs baseline: 1.1691x; 1.1691x over previous
//
#include <hip/hip_runtime.h>

typedef __bf16 bf16x8 __attribute__((ext_vector_type(8)));
typedef float  f32x4  __attribute__((ext_vector_type(4)));
typedef unsigned short u16;
typedef unsigned int   u32;
typedef long long      i64;

__device__ __forceinline__ float b2f(u16 x){ return __uint_as_float(((u32)x) << 16); }
__device__ __forceinline__ u16 f2b(float x){
  u32 u = __float_as_uint(x);
  return (u16)((u + 0x7FFFu + ((u >> 16) & 1u)) >> 16);
}

// flags[0] = 1 if float tensors are f32 on device (else bf16)
// flags[1] = 1 if edge_index is int64 on device (else int32)
__global__ __launch_bounds__(256) void k_detect(const u16* __restrict__ x,
                                                const u32* __restrict__ ei,
                                                int* __restrict__ flags){
  __shared__ int sh[2];
  int t = threadIdx.x;
  if (t < 2) sh[t] = 0;
  __syncthreads();
  int sane = 0;
  for (int i = t; i < 4096; i += 256){
    u16 u = x[i]; u32 e = (u >> 7) & 0xFFu;
    if (u == 0 || (e >= 0x70u && e <= 0x8Fu)) sane++;
  }
  int nz = 0;
  for (int i = t; i < 1024; i += 256)
    if (ei[2*i + 1] != 0u) nz++;
  atomicAdd(&sh[0], sane);
  atomicAdd(&sh[1], nz);
  __syncthreads();
  if (t == 0){
    flags[0] = (sh[0] < 3500) ? 1 : 0;
    flags[1] = (sh[1] == 0) ? 1 : 0;
  }
}

__device__ __forceinline__ int ld_idx(const void* ei, long long j, int is64){
  return is64 ? (int)((const i64*)ei)[j] : ((const int*)ei)[j];
}
__device__ __forceinline__ float ld_f(const void* p, int j, int isf32){
  return isf32 ? ((const float*)p)[j] : b2f(((const u16*)p)[j]);
}

__global__ void k_zero(int* __restrict__ a, int* __restrict__ b, int n){
  int i = blockIdx.x*blockDim.x + threadIdx.x;
  if (i < n){ a[i] = 0; b[i] = 0; }
}

__global__ void k_deg(const void* __restrict__ ei, int E, int n,
                      int* __restrict__ deg, const int* __restrict__ flags){
  int e = blockIdx.x*blockDim.x + threadIdx.x;
  if (e >= E) return;
  int is64 = flags[1];
  int d = ld_idx(ei, (long long)E + e, is64);
  if ((unsigned)d < (unsigned)n) atomicAdd(&deg[d], 1);
}

// ---- hierarchical scan: A) block partial sums, B) scan partials, C) local scan ----
// each block covers 1024 elements (256 threads x 4)
__global__ __launch_bounds__(256) void k_scanA(const int* __restrict__ deg, int n,
                                               int* __restrict__ bsum){
  __shared__ int sh[256];
  int t = threadIdx.x;
  int base = blockIdx.x*1024 + t*4;
  int s = 0;
  #pragma unroll
  for (int i = 0; i < 4; ++i){ int idx = base + i; if (idx < n) s += deg[idx]; }
  sh[t] = s; __syncthreads();
  for (int off = 128; off; off >>= 1){
    if (t < off) sh[t] += sh[t + off];
    __syncthreads();
  }
  if (t == 0) bsum[blockIdx.x] = sh[0];
}

__global__ __launch_bounds__(256) void k_scanB(int* __restrict__ bsum, int nB,
                                               int* __restrict__ rowptr, int n){
  __shared__ int sh[256];
  int t = threadIdx.x;
  int v = (t < nB) ? bsum[t] : 0;
  sh[t] = v; __syncthreads();
  for (int off = 1; off < 256; off <<= 1){
    int u = 0; if (t >= off) u = sh[t - off];
    __syncthreads(); sh[t] += u; __syncthreads();
  }
  if (t < nB) bsum[t] = sh[t] - v;   // exclusive
  if (t == 255) rowptr[n] = sh[255];
}

__global__ __launch_bounds__(256) void k_scanC(const int* __restrict__ deg, int n,
                                               const int* __restrict__ bsum,
                                               int* __restrict__ rowptr){
  __shared__ int sh[256];
  int t = threadIdx.x;
  int base = blockIdx.x*1024 + t*4;
  int d[4]; int s = 0;
  #pragma unroll
  for (int i = 0; i < 4; ++i){ int idx = base + i; d[i] = (idx < n) ? deg[idx] : 0; s += d[i]; }
  sh[t] = s; __syncthreads();
  for (int off = 1; off < 256; off <<= 1){
    int u = 0; if (t >= off) u = sh[t - off];
    __syncthreads(); sh[t] += u; __syncthreads();
  }
  int run = bsum[blockIdx.x] + sh[t] - s;
  #pragma unroll
  for (int i = 0; i < 4; ++i){
    int idx = base + i;
    if (idx < n){ rowptr[idx] = run; run += d[i]; }
  }
}

__global__ void k_dis(const int* __restrict__ deg, float* __restrict__ dis, int n){
  int v = blockIdx.x*blockDim.x + threadIdx.x;
  if (v < n) dis[v] = rsqrtf((float)(deg[v] + 1));
}

__global__ void k_fill(const void* __restrict__ ei, int E, int n,
                       const int* __restrict__ rowptr, int* __restrict__ cursor,
                       int* __restrict__ colx, const int* __restrict__ flags){
  int e = blockIdx.x*blockDim.x + threadIdx.x;
  if (e >= E) return;
  int is64 = flags[1];
  int d = ld_idx(ei, (long long)E + e, is64);
  int s = ld_idx(ei, e, is64);
  if ((unsigned)d < (unsigned)n && (unsigned)s < (unsigned)n){
    int p = atomicAdd(&cursor[d], 1);
    colx[rowptr[d] + p] = s;
  }
}

// pre-shuffle W (128x128) into MFMA B-fragment order (bf16 out)
__global__ __launch_bounds__(64) void k_shufW(const void* __restrict__ W, u16* __restrict__ Ws,
                                              const int* __restrict__ flags){
  int f = flags[0];
  int bid = blockIdx.x;          // 0..31
  int nt = bid >> 2, kk = bid & 3;
  int l = threadIdx.x;
  int g = l >> 4, mr = l & 15;
  int nn = nt*16 + mr;
  #pragma unroll
  for (int i = 0; i < 8; ++i){
    int k = kk*32 + g*4 + (i & 3) + ((i >> 2) << 4);
    u16 w = f ? f2b(((const float*)W)[k*128 + nn]) : ((const u16*)W)[k*128 + nn];
    Ws[(size_t)(bid*64 + l)*8 + i] = w;
  }
}

// T = (A @ W) * dis[row], bf16 out. One wave per 16-row tile.
__global__ __launch_bounds__(256) void k_gemm(const void* __restrict__ A, int aExt,
    const u16* __restrict__ Ws, const float* __restrict__ dis,
    u16* __restrict__ T, int nTiles, const int* __restrict__ flags)
{
  int wave = threadIdx.x >> 6, lane = threadIdx.x & 63;
  int tile = blockIdx.x*4 + wave;
  if (tile >= nTiles) return;
  int g = lane >> 4, mr = lane & 15;
  int f = aExt ? flags[0] : 0;
  union U8 { ushort4 q[2]; u16 s[8]; bf16x8 b; };
  bf16x8 a[4];
  if (f){
    const float* ap = (const float*)A + (size_t)(tile*16 + mr)*128;
    #pragma unroll
    for (int kk = 0; kk < 4; ++kk){
      float4 p = *(const float4*)(ap + kk*32 + g*4);
      float4 q = *(const float4*)(ap + kk*32 + g*4 + 16);
      U8 u;
      u.s[0]=f2b(p.x); u.s[1]=f2b(p.y); u.s[2]=f2b(p.z); u.s[3]=f2b(p.w);
      u.s[4]=f2b(q.x); u.s[5]=f2b(q.y); u.s[6]=f2b(q.z); u.s[7]=f2b(q.w);
      a[kk] = u.b;
    }
  } else {
    const u16* ap = (const u16*)A + (size_t)(tile*16 + mr)*128;
    #pragma unroll
    for (int kk = 0; kk < 4; ++kk){
      U8 u;
      u.q[0] = *(const ushort4*)(ap + kk*32 + g*4);
      u.q[1] = *(const ushort4*)(ap + kk*32 + g*4 + 16);
      a[kk] = u.b;
    }
  }
  float dj[4];
  #pragma unroll
  for (int j = 0; j < 4; ++j) dj[j] = dis[tile*16 + g*4 + j];
  #pragma unroll
  for (int nt = 0; nt < 8; ++nt){
    f32x4 acc = {0.f,0.f,0.f,0.f};
    #pragma unroll
    for (int kk = 0; kk < 4; ++kk){
      bf16x8 b = *(const bf16x8*)(Ws + (size_t)((nt*4 + kk)*64 + lane)*8);
      acc = __builtin_amdgcn_mfma_f32_16x16x32_bf16(a[kk], b, acc, 0, 0, 0);
    }
    int nn = nt*16 + mr;
    #pragma unroll
    for (int j = 0; j < 4; ++j){
      int row = tile*16 + g*4 + j;
      T[(size_t)row*128 + nn] = f2b(acc[j] * dj[j]);
    }
  }
}

// aggregation + bias + epilogue. One wave per node.
// colx entries for the row are loaded cooperatively (64 at a time) and
// broadcast via shfl so the T-gathers pipeline without a dependent-load chain.
template<int MODE>
__global__ __launch_bounds__(64) void k_agg(const u16* __restrict__ T,
    const int* __restrict__ rowptr, const int* __restrict__ colx,
    const float* __restrict__ dis, const void* __restrict__ bias,
    const void* __restrict__ lg, const void* __restrict__ lb,
    void* __restrict__ outA, int n, const int* __restrict__ flags)
{
  int v = blockIdx.x; if (v >= n) return;
  int f = flags[0];
  int l = threadIdx.x, d0 = l*2;
  u32 self = *(const u32*)(T + (size_t)v*128 + d0);
  float a0 = b2f((u16)(self & 0xffff)), a1 = b2f((u16)(self >> 16));
  int s = rowptr[v], e = rowptr[v+1];
  for (int base = s; base < e; base += 64){
    int cnt = e - base; if (cnt > 64) cnt = 64;
    int my = (base + l < e) ? colx[base + l] : 0;
    for (int i = 0; i < cnt; ++i){
      int nb = __shfl(my, i);
      if ((unsigned)nb >= (unsigned)n) continue;
      u32 u = *(const u32*)(T + (size_t)nb*128 + d0);
      a0 += b2f((u16)(u & 0xffff));
      a1 += b2f((u16)(u >> 16));
    }
  }
  float sc = dis[v];
  float x0 = fmaf(a0, sc, ld_f(bias, d0,   f));
  float x1 = fmaf(a1, sc, ld_f(bias, d0+1, f));
  if (MODE == 0){
    x0 = fmaxf(x0, 0.f); x1 = fmaxf(x1, 0.f);
    float sum = x0 + x1;
    #pragma unroll
    for (int off = 32; off; off >>= 1) sum += __shfl_xor(sum, off);
    float mu = sum * (1.f/128.f);
    float e0 = x0 - mu, e1 = x1 - mu;
    float vs = e0*e0 + e1*e1;
    #pragma unroll
    for (int off = 32; off; off >>= 1) vs += __shfl_xor(vs, off);
    float inv = rsqrtf(vs*(1.f/128.f) + 1e-5f);
    u16* oa = (u16*)outA;
    oa[(size_t)v*128 + d0]   = f2b(e0*inv*ld_f(lg, d0,   f) + ld_f(lb, d0,   f));
    oa[(size_t)v*128 + d0+1] = f2b(e1*inv*ld_f(lg, d0+1, f) + ld_f(lb, d0+1, f));
  } else {
    if (f){
      float* oa = (float*)outA;
      oa[(size_t)v*128 + d0]   = x0;
      oa[(size_t)v*128 + d0+1] = x1;
    } else {
      u16* oa = (u16*)outA;
      oa[(size_t)v*128 + d0]   = f2b(x0);
      oa[(size_t)v*128 + d0+1] = f2b(x1);
    }
  }
}

// collapse post_mp: Wc = mpW1 @ mpW2 (128x40), bc = mpb1 @ mpW2 + mpb2
__global__ __launch_bounds__(128) void k_wc(const void* __restrict__ mpW1, const void* __restrict__ mpb1,
    const void* __restrict__ mpW2, const void* __restrict__ mpb2,
    float* __restrict__ Wc, float* __restrict__ bc, const int* __restrict__ flags)
{
  int f = flags[0];
  int c = blockIdx.x;   // 0..39
  int k = threadIdx.x;  // 0..127
  float acc = 0.f;
  for (int j = 0; j < 128; ++j)
    acc += ld_f(mpW1, k*128 + j, f) * ld_f(mpW2, j*40 + c, f);
  Wc[k*40 + c] = acc;
  if (k == 0){
    float b = ld_f(mpb2, c, f);
    for (int j = 0; j < 128; ++j) b += ld_f(mpb1, j, f) * ld_f(mpW2, j*40 + c, f);
    bc[c] = b;
  }
}

// logits + log_softmax from emb (applies relu on the fly). One wave per node.
__global__ __launch_bounds__(64) void k_logits(const float* __restrict__ Wc,
    const float* __restrict__ bc, void* __restrict__ dout, int n,
    const int* __restrict__ flags)
{
  int v = blockIdx.x; if (v >= n) return;
  int f = flags[0];
  int c = threadIdx.x;
  float acc = -3.0e38f;
  if (c < 40){
    acc = bc[c];
    if (f){
      const float* h = (const float*)dout + (size_t)v*128;
      for (int k = 0; k < 128; ++k) acc = fmaf(fmaxf(h[k], 0.f), Wc[k*40 + c], acc);
    } else {
      const u16* h = (const u16*)dout + (size_t)v*128;
      for (int k = 0; k < 128; ++k) acc = fmaf(fmaxf(b2f(h[k]), 0.f), Wc[k*40 + c], acc);
    }
  }
  float m = acc;
  #pragma unroll
  for (int off = 32; off; off >>= 1) m = fmaxf(m, __shfl_xor(m, off));
  float ex = (c < 40) ? expf(acc - m) : 0.f;
  float ssum = ex;
  #pragma unroll
  for (int off = 32; off; off >>= 1) ssum += __shfl_xor(ssum, off);
  if (c < 40){
    float r = acc - m - logf(ssum);
    if (f) ((float*)dout + (size_t)n*128)[(size_t)v*40 + c] = r;
    else   ((u16*) dout + (size_t)n*128)[(size_t)v*40 + c] = f2b(r);
  }
}

extern "C" void kernel_launch(void* const* d_in, const int* in_sizes, int n_in,
                              void* d_out, int out_size, void* d_ws, size_t ws_size,
                              hipStream_t stream)
{
  const int n = in_sizes[0] / 128;
  const int E = in_sizes[1] / 2;

  const void* x    = d_in[0];
  const void* ei   = d_in[1];
  const void* W1   = d_in[2];
  const void* b1   = d_in[3];
  const void* W2   = d_in[4];
  const void* b2   = d_in[5];
  const void* W3   = d_in[6];
  const void* b3   = d_in[7];
  const void* ln1g = d_in[8];
  const void* ln1b = d_in[9];
  const void* ln2g = d_in[10];
  const void* ln2b = d_in[11];
  const void* mpW1 = d_in[12];
  const void* mpb1 = d_in[13];
  const void* mpW2 = d_in[14];
  const void* mpb2 = d_in[15];

  u16* Hbuf = (u16*)d_out;  // d_out emb region doubles as H buffer until layer 3

  char* w = (char*)d_ws;
  size_t off = 0;
  auto alloc = [&](size_t bytes)->char*{
    char* p = w + off; off = (off + bytes + 255) & ~(size_t)255; return p;
  };
  int*   flags = (int*)  alloc(256);
  float* dis   = (float*)alloc((size_t)n*4);
  int*   deg   = (int*)  alloc((size_t)n*4);
  int*   rowp  = (int*)  alloc((size_t)(n+1)*4);
  int*   curs  = (int*)  alloc((size_t)n*4);
  int*   bsum  = (int*)  alloc(1024);
  int*   colx  = (int*)  alloc((size_t)E*4);
  u16*   T     = (u16*)  alloc((size_t)n*128*2);
  u16*   Ws    = (u16*)  alloc((size_t)128*128*2);
  float* Wc    = (float*)alloc((size_t)128*40*4);
  float* bc    = (float*)alloc((size_t)64*4);

  int gE = (E + 255) / 256;
  int gN = (n + 255) / 256;
  int nB = (n + 1023) / 1024;   // blocks for the hierarchical scan (<=256)

  k_detect<<<1, 256, 0, stream>>>((const u16*)x, (const u32*)ei, flags);
  k_zero  <<<gN, 256, 0, stream>>>(deg, curs, n);
  k_deg   <<<gE, 256, 0, stream>>>(ei, E, n, deg, flags);
  k_scanA <<<nB, 256, 0, stream>>>(deg, n, bsum);
  k_scanB <<<1, 256, 0, stream>>>(bsum, nB, rowp, n);
  k_scanC <<<nB, 256, 0, stream>>>(deg, n, bsum, rowp);
  k_dis   <<<gN, 256, 0, stream>>>(deg, dis, n);
  k_fill  <<<gE, 256, 0, stream>>>(ei, E, n, rowp, curs, colx, flags);
  k_wc    <<<40, 128, 0, stream>>>(mpW1, mpb1, mpW2, mpb2, Wc, bc, flags);

  int nTiles = (n + 15) / 16;
  int gG = (nTiles + 3) / 4;

  // layer 0
  k_shufW<<<32, 64, 0, stream>>>(W1, Ws, flags);
  k_gemm <<<gG, 256, 0, stream>>>(x, 1, Ws, dis, T, nTiles, flags);
  k_agg<0><<<n, 64, 0, stream>>>(T, rowp, colx, dis, b1, ln1g, ln1b, Hbuf, n, flags);
  // layer 1
  k_shufW<<<32, 64, 0, stream>>>(W2, Ws, flags);
  k_gemm <<<gG, 256, 0, stream>>>(Hbuf, 0, Ws, dis, T, nTiles, flags);
  k_agg<0><<<n, 64, 0, stream>>>(T, rowp, colx, dis, b2, ln2g, ln2b, Hbuf, n, flags);
  // layer 2: emb -> d_out
  k_shufW<<<32, 64, 0, stream>>>(W3, Ws, flags);
  k_gemm <<<gG, 256, 0, stream>>>(Hbuf, 0, Ws, dis, T, nTiles, flags);
  k_agg<1><<<n, 64, 0, stream>>>(T, rowp, colx, dis, b3, nullptr, nullptr, d_out, n, flags);
  // post_mp collapsed + log_softmax
  k_logits<<<n, 64, 0, stream>>>(Wc, bc, d_out, n, flags);
}

// Round 4
// 326.254 us; speedup vs baseline: 1.5519x; 1.3274x over previous
//
#include <hip/hip_runtime.h>

typedef __bf16 bf16x8 __attribute__((ext_vector_type(8)));
typedef float  f32x4  __attribute__((ext_vector_type(4)));
typedef unsigned short u16;
typedef unsigned int   u32;
typedef long long      i64;

__device__ __forceinline__ float b2f(u16 x){ return __uint_as_float(((u32)x) << 16); }
__device__ __forceinline__ u16 f2b(float x){
  u32 u = __float_as_uint(x);
  return (u16)((u + 0x7FFFu + ((u >> 16) & 1u)) >> 16);
}

// flags[0] = 1 if float tensors are f32 on device (else bf16)
// flags[1] = 1 if edge_index is int64 on device (else int32)
__global__ __launch_bounds__(256) void k_detect(const u16* __restrict__ x,
                                                const u32* __restrict__ ei,
                                                int* __restrict__ flags){
  __shared__ int sh[2];
  int t = threadIdx.x;
  if (t < 2) sh[t] = 0;
  __syncthreads();
  int sane = 0;
  for (int i = t; i < 4096; i += 256){
    u16 u = x[i]; u32 e = (u >> 7) & 0xFFu;
    if (u == 0 || (e >= 0x70u && e <= 0x8Fu)) sane++;
  }
  int nz = 0;
  for (int i = t; i < 1024; i += 256)
    if (ei[2*i + 1] != 0u) nz++;
  atomicAdd(&sh[0], sane);
  atomicAdd(&sh[1], nz);
  __syncthreads();
  if (t == 0){
    flags[0] = (sh[0] < 3500) ? 1 : 0;
    flags[1] = (sh[1] == 0) ? 1 : 0;
  }
}

__device__ __forceinline__ int ld_idx(const void* ei, long long j, int is64){
  return is64 ? (int)((const i64*)ei)[j] : ((const int*)ei)[j];
}
__device__ __forceinline__ float ld_f(const void* p, int j, int isf32){
  return isf32 ? ((const float*)p)[j] : b2f(((const u16*)p)[j]);
}

__global__ void k_zero(int* __restrict__ a, int* __restrict__ b, int n){
  int i = blockIdx.x*blockDim.x + threadIdx.x;
  if (i < n){ a[i] = 0; b[i] = 0; }
}

__global__ void k_deg(const void* __restrict__ ei, int E, int n,
                      int* __restrict__ deg, const int* __restrict__ flags){
  int e = blockIdx.x*blockDim.x + threadIdx.x;
  if (e >= E) return;
  int is64 = flags[1];
  int d = ld_idx(ei, (long long)E + e, is64);
  if ((unsigned)d < (unsigned)n) atomicAdd(&deg[d], 1);
}

// ---- hierarchical scan ----
__global__ __launch_bounds__(256) void k_scanA(const int* __restrict__ deg, int n,
                                               int* __restrict__ bsum){
  __shared__ int sh[256];
  int t = threadIdx.x;
  int base = blockIdx.x*1024 + t*4;
  int s = 0;
  #pragma unroll
  for (int i = 0; i < 4; ++i){ int idx = base + i; if (idx < n) s += deg[idx]; }
  sh[t] = s; __syncthreads();
  for (int off = 128; off; off >>= 1){
    if (t < off) sh[t] += sh[t + off];
    __syncthreads();
  }
  if (t == 0) bsum[blockIdx.x] = sh[0];
}

__global__ __launch_bounds__(256) void k_scanB(int* __restrict__ bsum, int nB,
                                               int* __restrict__ rowptr, int n){
  __shared__ int sh[256];
  int t = threadIdx.x;
  int v = (t < nB) ? bsum[t] : 0;
  sh[t] = v; __syncthreads();
  for (int off = 1; off < 256; off <<= 1){
    int u = 0; if (t >= off) u = sh[t - off];
    __syncthreads(); sh[t] += u; __syncthreads();
  }
  if (t < nB) bsum[t] = sh[t] - v;
  if (t == 255) rowptr[n] = sh[255];
}

// local scan + rowptr write + dis = rsqrt(deg+1)
__global__ __launch_bounds__(256) void k_scanC(const int* __restrict__ deg, int n,
                                               const int* __restrict__ bsum,
                                               int* __restrict__ rowptr,
                                               float* __restrict__ dis){
  __shared__ int sh[256];
  int t = threadIdx.x;
  int base = blockIdx.x*1024 + t*4;
  int d[4]; int s = 0;
  #pragma unroll
  for (int i = 0; i < 4; ++i){ int idx = base + i; d[i] = (idx < n) ? deg[idx] : 0; s += d[i]; }
  sh[t] = s; __syncthreads();
  for (int off = 1; off < 256; off <<= 1){
    int u = 0; if (t >= off) u = sh[t - off];
    __syncthreads(); sh[t] += u; __syncthreads();
  }
  int run = bsum[blockIdx.x] + sh[t] - s;
  #pragma unroll
  for (int i = 0; i < 4; ++i){
    int idx = base + i;
    if (idx < n){
      rowptr[idx] = run; run += d[i];
      dis[idx] = rsqrtf((float)(d[i] + 1));
    }
  }
}

__global__ void k_fill(const void* __restrict__ ei, int E, int n,
                       const int* __restrict__ rowptr, int* __restrict__ cursor,
                       int* __restrict__ colx, const int* __restrict__ flags){
  int e = blockIdx.x*blockDim.x + threadIdx.x;
  if (e >= E) return;
  int is64 = flags[1];
  int d = ld_idx(ei, (long long)E + e, is64);
  int s = ld_idx(ei, e, is64);
  if ((unsigned)d < (unsigned)n && (unsigned)s < (unsigned)n){
    int p = atomicAdd(&cursor[d], 1);
    colx[rowptr[d] + p] = s;
  }
}

// pre-shuffle W (128x128) into MFMA B-fragment order (bf16 out)
__global__ __launch_bounds__(64) void k_shufW(const void* __restrict__ W, u16* __restrict__ Ws,
                                              const int* __restrict__ flags){
  int f = flags[0];
  int bid = blockIdx.x;          // 0..31
  int nt = bid >> 2, kk = bid & 3;
  int l = threadIdx.x;
  int g = l >> 4, mr = l & 15;
  int nn = nt*16 + mr;
  #pragma unroll
  for (int i = 0; i < 8; ++i){
    int k = kk*32 + g*4 + (i & 3) + ((i >> 2) << 4);
    u16 w = f ? f2b(((const float*)W)[k*128 + nn]) : ((const u16*)W)[k*128 + nn];
    Ws[(size_t)(bid*64 + l)*8 + i] = w;
  }
}

// T = (A @ W) * dis[row], bf16 out. One wave per 16-row tile.
__global__ __launch_bounds__(256) void k_gemm(const void* __restrict__ A, int aExt,
    const u16* __restrict__ Ws, const float* __restrict__ dis,
    u16* __restrict__ T, int nTiles, const int* __restrict__ flags)
{
  int wave = threadIdx.x >> 6, lane = threadIdx.x & 63;
  int tile = blockIdx.x*4 + wave;
  if (tile >= nTiles) return;
  int g = lane >> 4, mr = lane & 15;
  int f = aExt ? flags[0] : 0;
  union U8 { ushort4 q[2]; u16 s[8]; bf16x8 b; };
  bf16x8 a[4];
  if (f){
    const float* ap = (const float*)A + (size_t)(tile*16 + mr)*128;
    #pragma unroll
    for (int kk = 0; kk < 4; ++kk){
      float4 p = *(const float4*)(ap + kk*32 + g*4);
      float4 q = *(const float4*)(ap + kk*32 + g*4 + 16);
      U8 u;
      u.s[0]=f2b(p.x); u.s[1]=f2b(p.y); u.s[2]=f2b(p.z); u.s[3]=f2b(p.w);
      u.s[4]=f2b(q.x); u.s[5]=f2b(q.y); u.s[6]=f2b(q.z); u.s[7]=f2b(q.w);
      a[kk] = u.b;
    }
  } else {
    const u16* ap = (const u16*)A + (size_t)(tile*16 + mr)*128;
    #pragma unroll
    for (int kk = 0; kk < 4; ++kk){
      U8 u;
      u.q[0] = *(const ushort4*)(ap + kk*32 + g*4);
      u.q[1] = *(const ushort4*)(ap + kk*32 + g*4 + 16);
      a[kk] = u.b;
    }
  }
  float dj[4];
  #pragma unroll
  for (int j = 0; j < 4; ++j) dj[j] = dis[tile*16 + g*4 + j];
  #pragma unroll
  for (int nt = 0; nt < 8; ++nt){
    f32x4 acc = {0.f,0.f,0.f,0.f};
    #pragma unroll
    for (int kk = 0; kk < 4; ++kk){
      bf16x8 b = *(const bf16x8*)(Ws + (size_t)((nt*4 + kk)*64 + lane)*8);
      acc = __builtin_amdgcn_mfma_f32_16x16x32_bf16(a[kk], b, acc, 0, 0, 0);
    }
    int nn = nt*16 + mr;
    #pragma unroll
    for (int j = 0; j < 4; ++j){
      int row = tile*16 + g*4 + j;
      T[(size_t)row*128 + nn] = f2b(acc[j] * dj[j]);
    }
  }
}

// aggregation + bias + epilogue. One wave per node, 4 nodes per block.
// Gather loop: cooperative colx load + shfl broadcast, unrolled x4 with
// 4 independent accumulator pairs so loads pipeline (no guard, no chain).
template<int MODE>
__global__ __launch_bounds__(256) void k_agg(const u16* __restrict__ T,
    const int* __restrict__ rowptr, const int* __restrict__ colx,
    const float* __restrict__ dis, const void* __restrict__ bias,
    const void* __restrict__ lg, const void* __restrict__ lb,
    void* __restrict__ outA, int n, const int* __restrict__ flags)
{
  int wave = threadIdx.x >> 6, l = threadIdx.x & 63;
  int v = blockIdx.x*4 + wave; if (v >= n) return;
  int f = flags[0];
  int d0 = l*2;
  u32 self = *(const u32*)(T + (size_t)v*128 + d0);
  float p0 = b2f((u16)(self & 0xffff)), p1 = b2f((u16)(self >> 16));
  float q0 = 0.f, q1 = 0.f, r0 = 0.f, r1 = 0.f, t0 = 0.f, t1 = 0.f;
  int s = rowptr[v], e = rowptr[v+1];
  for (int base = s; base < e; base += 64){
    int cnt = e - base; if (cnt > 64) cnt = 64;
    int my = (base + l < e) ? colx[base + l] : 0;
    int i = 0;
    for (; i + 4 <= cnt; i += 4){
      int nb0 = __shfl(my, i), nb1 = __shfl(my, i+1);
      int nb2 = __shfl(my, i+2), nb3 = __shfl(my, i+3);
      u32 u0 = *(const u32*)(T + (size_t)nb0*128 + d0);
      u32 u1 = *(const u32*)(T + (size_t)nb1*128 + d0);
      u32 u2 = *(const u32*)(T + (size_t)nb2*128 + d0);
      u32 u3 = *(const u32*)(T + (size_t)nb3*128 + d0);
      p0 += b2f((u16)(u0 & 0xffff)); p1 += b2f((u16)(u0 >> 16));
      q0 += b2f((u16)(u1 & 0xffff)); q1 += b2f((u16)(u1 >> 16));
      r0 += b2f((u16)(u2 & 0xffff)); r1 += b2f((u16)(u2 >> 16));
      t0 += b2f((u16)(u3 & 0xffff)); t1 += b2f((u16)(u3 >> 16));
    }
    for (; i < cnt; ++i){
      int nb = __shfl(my, i);
      u32 u = *(const u32*)(T + (size_t)nb*128 + d0);
      p0 += b2f((u16)(u & 0xffff)); p1 += b2f((u16)(u >> 16));
    }
  }
  float a0 = (p0 + q0) + (r0 + t0);
  float a1 = (p1 + q1) + (r1 + t1);
  float sc = dis[v];
  float x0 = fmaf(a0, sc, ld_f(bias, d0,   f));
  float x1 = fmaf(a1, sc, ld_f(bias, d0+1, f));
  if (MODE == 0){
    x0 = fmaxf(x0, 0.f); x1 = fmaxf(x1, 0.f);
    float sum = x0 + x1;
    #pragma unroll
    for (int off = 32; off; off >>= 1) sum += __shfl_xor(sum, off);
    float mu = sum * (1.f/128.f);
    float e0 = x0 - mu, e1 = x1 - mu;
    float vs = e0*e0 + e1*e1;
    #pragma unroll
    for (int off = 32; off; off >>= 1) vs += __shfl_xor(vs, off);
    float inv = rsqrtf(vs*(1.f/128.f) + 1e-5f);
    u16* oa = (u16*)outA;
    oa[(size_t)v*128 + d0]   = f2b(e0*inv*ld_f(lg, d0,   f) + ld_f(lb, d0,   f));
    oa[(size_t)v*128 + d0+1] = f2b(e1*inv*ld_f(lg, d0+1, f) + ld_f(lb, d0+1, f));
  } else {
    if (f){
      float* oa = (float*)outA;
      oa[(size_t)v*128 + d0]   = x0;
      oa[(size_t)v*128 + d0+1] = x1;
    } else {
      u16* oa = (u16*)outA;
      oa[(size_t)v*128 + d0]   = f2b(x0);
      oa[(size_t)v*128 + d0+1] = f2b(x1);
    }
  }
}

// collapse post_mp: Wc = mpW1 @ mpW2 (128x40 f32), bc = mpb1 @ mpW2 + mpb2
__global__ __launch_bounds__(128) void k_wc(const void* __restrict__ mpW1, const void* __restrict__ mpb1,
    const void* __restrict__ mpW2, const void* __restrict__ mpb2,
    float* __restrict__ Wc, float* __restrict__ bc, const int* __restrict__ flags)
{
  int f = flags[0];
  int c = blockIdx.x;   // 0..39
  int k = threadIdx.x;  // 0..127
  float acc = 0.f;
  for (int j = 0; j < 128; ++j)
    acc += ld_f(mpW1, k*128 + j, f) * ld_f(mpW2, j*40 + c, f);
  Wc[k*40 + c] = acc;
  if (k == 0){
    float b = ld_f(mpb2, c, f);
    for (int j = 0; j < 128; ++j) b += ld_f(mpb1, j, f) * ld_f(mpW2, j*40 + c, f);
    bc[c] = b;
  }
}

// shuffle Wc (128x40 f32) -> bf16 B-frags padded to 48 cols. 12 frags.
__global__ __launch_bounds__(64) void k_shufWc(const float* __restrict__ Wc, u16* __restrict__ Wcs){
  int bid = blockIdx.x;          // 0..11
  int nt = bid >> 2, kk = bid & 3;
  int l = threadIdx.x;
  int g = l >> 4, mr = l & 15;
  int nn = nt*16 + mr;
  #pragma unroll
  for (int i = 0; i < 8; ++i){
    int k = kk*32 + g*4 + (i & 3) + ((i >> 2) << 4);
    Wcs[(size_t)(bid*64 + l)*8 + i] = (nn < 40) ? f2b(Wc[k*40 + nn]) : (u16)0;
  }
}

// logits via MFMA + in-register log_softmax. One wave per 16-node tile.
// emb lives at d_out base (dtype per flag); lsm written past it.
__global__ __launch_bounds__(256) void k_logitsM(const u16* __restrict__ Wcs,
    const float* __restrict__ bc, void* __restrict__ dout, int n,
    const int* __restrict__ flags)
{
  int wave = threadIdx.x >> 6, lane = threadIdx.x & 63;
  int tile = blockIdx.x*4 + wave;
  int nTiles = n >> 4;
  if (tile >= nTiles) return;
  int f = flags[0];
  int g = lane >> 4, mr = lane & 15;
  union U8 { ushort4 q[2]; u16 s[8]; bf16x8 b; };
  bf16x8 a[4];
  if (f){
    const float* ap = (const float*)dout + (size_t)(tile*16 + mr)*128;
    #pragma unroll
    for (int kk = 0; kk < 4; ++kk){
      float4 p = *(const float4*)(ap + kk*32 + g*4);
      float4 q = *(const float4*)(ap + kk*32 + g*4 + 16);
      U8 u;
      u.s[0]=f2b(fmaxf(p.x,0.f)); u.s[1]=f2b(fmaxf(p.y,0.f));
      u.s[2]=f2b(fmaxf(p.z,0.f)); u.s[3]=f2b(fmaxf(p.w,0.f));
      u.s[4]=f2b(fmaxf(q.x,0.f)); u.s[5]=f2b(fmaxf(q.y,0.f));
      u.s[6]=f2b(fmaxf(q.z,0.f)); u.s[7]=f2b(fmaxf(q.w,0.f));
      a[kk] = u.b;
    }
  } else {
    const u16* ap = (const u16*)dout + (size_t)(tile*16 + mr)*128;
    #pragma unroll
    for (int kk = 0; kk < 4; ++kk){
      U8 u;
      u.q[0] = *(const ushort4*)(ap + kk*32 + g*4);
      u.q[1] = *(const ushort4*)(ap + kk*32 + g*4 + 16);
      #pragma unroll
      for (int i = 0; i < 8; ++i) u.s[i] = (u.s[i] & 0x8000u) ? (u16)0 : u.s[i];  // relu
      a[kk] = u.b;
    }
  }
  f32x4 acc[3];
  #pragma unroll
  for (int nt = 0; nt < 3; ++nt){
    f32x4 c4 = {0.f,0.f,0.f,0.f};
    #pragma unroll
    for (int kk = 0; kk < 4; ++kk){
      bf16x8 b = *(const bf16x8*)(Wcs + (size_t)((nt*4 + kk)*64 + lane)*8);
      c4 = __builtin_amdgcn_mfma_f32_16x16x32_bf16(a[kk], b, c4, 0, 0, 0);
    }
    acc[nt] = c4;
  }
  float bcv[3]; bool valid[3];
  #pragma unroll
  for (int nt = 0; nt < 3; ++nt){
    int c = nt*16 + mr;
    valid[nt] = (c < 40);
    bcv[nt] = valid[nt] ? bc[c] : 0.f;
  }
  float* of = (float*)dout + (size_t)n*128;
  u16*  ob = (u16*) dout + (size_t)n*128;
  #pragma unroll
  for (int j = 0; j < 4; ++j){
    float l0 = valid[0] ? acc[0][j] + bcv[0] : -3.0e38f;
    float l1 = valid[1] ? acc[1][j] + bcv[1] : -3.0e38f;
    float l2 = valid[2] ? acc[2][j] + bcv[2] : -3.0e38f;
    float m = fmaxf(l0, fmaxf(l1, l2));
    #pragma unroll
    for (int off = 8; off; off >>= 1) m = fmaxf(m, __shfl_xor(m, off));
    float ssum = (valid[0] ? expf(l0 - m) : 0.f)
               + (valid[1] ? expf(l1 - m) : 0.f)
               + (valid[2] ? expf(l2 - m) : 0.f);
    #pragma unroll
    for (int off = 8; off; off >>= 1) ssum += __shfl_xor(ssum, off);
    float lgs = m + logf(ssum);
    int node = tile*16 + g*4 + j;
    #pragma unroll
    for (int nt = 0; nt < 3; ++nt){
      if (valid[nt]){
        int c = nt*16 + mr;
        float r = (nt==0 ? l0 : (nt==1 ? l1 : l2)) - lgs;
        if (f) of[(size_t)node*40 + c] = r;
        else   ob[(size_t)node*40 + c] = f2b(r);
      }
    }
  }
}

extern "C" void kernel_launch(void* const* d_in, const int* in_sizes, int n_in,
                              void* d_out, int out_size, void* d_ws, size_t ws_size,
                              hipStream_t stream)
{
  const int n = in_sizes[0] / 128;
  const int E = in_sizes[1] / 2;

  const void* x    = d_in[0];
  const void* ei   = d_in[1];
  const void* W1   = d_in[2];
  const void* b1   = d_in[3];
  const void* W2   = d_in[4];
  const void* b2   = d_in[5];
  const void* W3   = d_in[6];
  const void* b3   = d_in[7];
  const void* ln1g = d_in[8];
  const void* ln1b = d_in[9];
  const void* ln2g = d_in[10];
  const void* ln2b = d_in[11];
  const void* mpW1 = d_in[12];
  const void* mpb1 = d_in[13];
  const void* mpW2 = d_in[14];
  const void* mpb2 = d_in[15];

  u16* Hbuf = (u16*)d_out;  // d_out emb region doubles as H buffer until layer 3

  char* w = (char*)d_ws;
  size_t off = 0;
  auto alloc = [&](size_t bytes)->char*{
    char* p = w + off; off = (off + bytes + 255) & ~(size_t)255; return p;
  };
  int*   flags = (int*)  alloc(256);
  float* dis   = (float*)alloc((size_t)n*4);
  int*   deg   = (int*)  alloc((size_t)n*4);
  int*   rowp  = (int*)  alloc((size_t)(n+1)*4);
  int*   curs  = (int*)  alloc((size_t)n*4);
  int*   bsum  = (int*)  alloc(1024);
  int*   colx  = (int*)  alloc((size_t)E*4 + 256);
  u16*   T     = (u16*)  alloc((size_t)n*128*2);
  u16*   Ws    = (u16*)  alloc((size_t)128*128*2);
  float* Wc    = (float*)alloc((size_t)128*40*4);
  float* bc    = (float*)alloc((size_t)64*4);
  u16*   Wcs   = (u16*)  alloc((size_t)12*64*8*2);

  int gE = (E + 255) / 256;
  int gN = (n + 255) / 256;
  int nB = (n + 1023) / 1024;

  k_detect<<<1, 256, 0, stream>>>((const u16*)x, (const u32*)ei, flags);
  k_zero  <<<gN, 256, 0, stream>>>(deg, curs, n);
  k_deg   <<<gE, 256, 0, stream>>>(ei, E, n, deg, flags);
  k_scanA <<<nB, 256, 0, stream>>>(deg, n, bsum);
  k_scanB <<<1, 256, 0, stream>>>(bsum, nB, rowp, n);
  k_scanC <<<nB, 256, 0, stream>>>(deg, n, bsum, rowp, dis);
  k_fill  <<<gE, 256, 0, stream>>>(ei, E, n, rowp, curs, colx, flags);
  k_wc    <<<40, 128, 0, stream>>>(mpW1, mpb1, mpW2, mpb2, Wc, bc, flags);
  k_shufWc<<<12, 64, 0, stream>>>(Wc, Wcs);

  int nTiles = (n + 15) / 16;
  int gG = (nTiles + 3) / 4;
  int gA = (n + 3) / 4;

  // layer 0
  k_shufW<<<32, 64, 0, stream>>>(W1, Ws, flags);
  k_gemm <<<gG, 256, 0, stream>>>(x, 1, Ws, dis, T, nTiles, flags);
  k_agg<0><<<gA, 256, 0, stream>>>(T, rowp, colx, dis, b1, ln1g, ln1b, Hbuf, n, flags);
  // layer 1
  k_shufW<<<32, 64, 0, stream>>>(W2, Ws, flags);
  k_gemm <<<gG, 256, 0, stream>>>(Hbuf, 0, Ws, dis, T, nTiles, flags);
  k_agg<0><<<gA, 256, 0, stream>>>(T, rowp, colx, dis, b2, ln2g, ln2b, Hbuf, n, flags);
  // layer 2: emb -> d_out
  k_shufW<<<32, 64, 0, stream>>>(W3, Ws, flags);
  k_gemm <<<gG, 256, 0, stream>>>(Hbuf, 0, Ws, dis, T, nTiles, flags);
  k_agg<1><<<gA, 256, 0, stream>>>(T, rowp, colx, dis, b3, nullptr, nullptr, d_out, n, flags);
  // post_mp collapsed + log_softmax (MFMA)
  k_logitsM<<<gG, 256, 0, stream>>>(Wcs, bc, d_out, n, flags);
}